// Round 11
// baseline (222.309 us; speedup 1.0000x reference)
//
#include <hip/hip_runtime.h>
#include <hip/hip_bf16.h>
#include <math.h>

#define N0v 200000
#define N1v 50000
#define N2v 10000
#define Dv  256
#define Cv  40
#define DEGv 10

typedef __attribute__((ext_vector_type(8))) short          s16x8;
typedef __attribute__((ext_vector_type(8))) unsigned short u16x8;
typedef __attribute__((ext_vector_type(4))) float          f32x4;

static __device__ __forceinline__ unsigned short f2bf(float f) {
    __hip_bfloat16 h = __float2bfloat16(f);
    return *reinterpret_cast<unsigned short*>(&h);
}
static __device__ __forceinline__ float bf2f(unsigned short u) {
    __hip_bfloat16 h = *reinterpret_cast<__hip_bfloat16*>(&u);
    return __bfloat162float(h);
}

// async global -> LDS, 16B/lane, wave-uniform LDS base + lane*16 dest
static __device__ __forceinline__ void gload16(const void* g, void* l) {
    __builtin_amdgcn_global_load_lds(
        (const __attribute__((address_space(1))) unsigned int*)g,
        (__attribute__((address_space(3))) unsigned int*)l, 16, 0, 0);
}

// ---- conv+prep: blocks [0,25000) convert x (200000x256 f32) -> xb bf16;
//      blocks [25000,26024) transpose 4 weight pairs -> WT[n][k] bf16.
__global__ __launch_bounds__(256) void conv_prep_kernel(
    const float* __restrict__ x, unsigned short* __restrict__ xb,
    const float* __restrict__ Wl0, const float* __restrict__ Wr0,
    const float* __restrict__ Wl1, const float* __restrict__ Wr1,
    const float* __restrict__ Wl2, const float* __restrict__ Wr2,
    const float* __restrict__ Wl3, const float* __restrict__ Wr3,
    unsigned short* __restrict__ WT0, unsigned short* __restrict__ WT1,
    unsigned short* __restrict__ WT2, unsigned short* __restrict__ WT3)
{
    const int b = blockIdx.x;
    const int tid = threadIdx.x;
    if (b < 25000) {
        const size_t i = ((size_t)b * 256 + tid) * 8;
        float4 v0 = *(const float4*)(x + i);
        float4 v1 = *(const float4*)(x + i + 4);
        unsigned short o[8] = { f2bf(v0.x), f2bf(v0.y), f2bf(v0.z), f2bf(v0.w),
                                f2bf(v1.x), f2bf(v1.y), f2bf(v1.z), f2bf(v1.w) };
        *(u16x8*)(xb + i) = *(u16x8*)o;
    } else {
        const int idx = b - 25000;
        const int p = idx >> 8;
        const int n = idx & 255;
        const float* Wl = (p == 0) ? Wl0 : (p == 1) ? Wl1 : (p == 2) ? Wl2 : Wl3;
        const float* Wr = (p == 0) ? Wr0 : (p == 1) ? Wr1 : (p == 2) ? Wr2 : Wr3;
        unsigned short* WT = (p == 0) ? WT0 : (p == 1) ? WT1 : (p == 2) ? WT2 : WT3;
        WT[(size_t)n * 512 + tid]       = f2bf(Wl[(size_t)tid * Dv + n]);
        WT[(size_t)n * 512 + 256 + tid] = f2bf(Wr[(size_t)tid * Dv + n]);
    }
}

// ---- layer-0 aggregation from bf16 table: one load feeds mean AND max.
__global__ __launch_bounds__(256) void agg0_kernel(
    const unsigned short* __restrict__ xb, const int* __restrict__ row,
    unsigned short* __restrict__ om, unsigned short* __restrict__ ox)
{
    const int t = blockIdx.x * 8 + (threadIdx.x >> 5);
    const int c = threadIdx.x & 31;
    const int eb = t * DEGv;
    float s[8] = {};
    float mx[8] = { -INFINITY, -INFINITY, -INFINITY, -INFINITY,
                    -INFINITY, -INFINITY, -INFINITY, -INFINITY };
#pragma unroll
    for (int k = 0; k < DEGv; ++k) {
        const int r = row[eb + k];
        u16x8 v = ((const u16x8*)xb)[(size_t)r * 32 + c];
#pragma unroll
        for (int j = 0; j < 8; ++j) {
            const float f = bf2f(v[j]);
            s[j] += f;
            mx[j] = fmaxf(mx[j], f);
        }
    }
    const float inv = 1.0f / DEGv;
    unsigned short osum[8], omax[8];
#pragma unroll
    for (int j = 0; j < 8; ++j) { osum[j] = f2bf(s[j] * inv); omax[j] = f2bf(mx[j]); }
    *(u16x8*)&om[(size_t)t * Dv + c * 8] = *(u16x8*)osum;
    *(u16x8*)&ox[(size_t)t * Dv + c * 8] = *(u16x8*)omax;
}

// ---- layer-1 aggregation: gather bf16 (u16x8/lane), write mean & max bf16
__global__ __launch_bounds__(256) void agg1_kernel(
    const unsigned short* __restrict__ hm, const unsigned short* __restrict__ hx,
    const int* __restrict__ row,
    unsigned short* __restrict__ om, unsigned short* __restrict__ ox)
{
    const int t = blockIdx.x * 8 + (threadIdx.x >> 5);
    const int c = threadIdx.x & 31;
    const int eb = t * DEGv;
    float s[8] = {};
    float mx[8] = { -INFINITY, -INFINITY, -INFINITY, -INFINITY,
                    -INFINITY, -INFINITY, -INFINITY, -INFINITY };
#pragma unroll
    for (int k = 0; k < DEGv; ++k) {
        const int r = row[eb + k];
        u16x8 vm = ((const u16x8*)hm)[(size_t)r * 32 + c];
        u16x8 vx = ((const u16x8*)hx)[(size_t)r * 32 + c];
#pragma unroll
        for (int j = 0; j < 8; ++j) {
            s[j]  += bf2f(vm[j]);
            mx[j]  = fmaxf(mx[j], bf2f(vx[j]));
        }
    }
    const float inv = 1.0f / DEGv;
    unsigned short osum[8], omax[8];
#pragma unroll
    for (int j = 0; j < 8; ++j) { osum[j] = f2bf(s[j] * inv); omax[j] = f2bf(mx[j]); }
    *(u16x8*)&om[(size_t)t * Dv + c * 8] = *(u16x8*)osum;
    *(u16x8*)&ox[(size_t)t * Dv + c * 8] = *(u16x8*)omax;
}

// ---- bf16 MFMA GEMM, counted-vmcnt 2-deep pipeline, 256x256 tile:
// out_z = [relu]( [A1_z|A2] (Mx512) @ WT_z^T + bias_z )
// BM=256, BN=256, BK=32, 512 threads = 8 waves (2M x 4N), wave-tile 128x64.
// LDS paired-line layout (r10-proven): line L (64 elems) = rows {2L,2L+1} x
// 32 k; phys 8-elem slot s of line L holds logical sig = s ^ (L&7), with
// sig = (row&1)*4 + q.  Staging: 4 x gload16/thread/stage, linear dest,
// pre-swizzled source.  Schedule/iter (r10-proven): vmcnt(4); barrier;
// ds_read + 32 MFMA; lgkmcnt(0); barrier; STAGE(t+2).  vmcnt never drains
// to 0 in the main loop.
template<int RELU, int OUTBF>
__global__ __launch_bounds__(512) void gemm_pipe_kernel(
    const unsigned short* __restrict__ A1a, const unsigned short* __restrict__ A1b,
    const unsigned short* __restrict__ A2,
    const unsigned short* __restrict__ WTa, const unsigned short* __restrict__ WTb,
    const float* __restrict__ biasa, const float* __restrict__ biasb,
    void* outa, void* outb, int M, int ldc, int col_step)
{
    __shared__ unsigned short Asb[2][8192];   // 2 x 16 KB (256 rows x 32 k)
    __shared__ unsigned short Bsb[2][8192];   // 2 x 16 KB (256 n    x 32 k)

    const int z = blockIdx.z;
    const unsigned short* A1 = z ? A1b : A1a;
    const unsigned short* WT = z ? WTb : WTa;
    const float* bias = z ? biasb : biasa;
    void* outp = z ? outb : outa;
    const int col_off = z * col_step;

    const int tid  = threadIdx.x;
    const int lane = tid & 63;
    const int w    = tid >> 6;
    const int wrow = w >> 2;          // 0..1 (x128 rows)
    const int wcol = w & 3;           // 0..3 (x64 cols)
    const int m0   = blockIdx.x * 256;

    // A staging descriptors: 2 positions/thread (1024 x 16B = 16 KB)
    const unsigned short* pA1s[2];
    const unsigned short* pA2s[2];
#pragma unroll
    for (int c = 0; c < 2; ++c) {
        const int p = tid + c * 512;
        const int L = p >> 3, s = p & 7;
        const int sig = s ^ (L & 7);
        int gm = m0 + 2 * L + (sig >> 2);
        if (gm >= M) gm = M - 1;
        pA1s[c] = A1 + (size_t)gm * Dv + ((sig & 3) << 3);
        pA2s[c] = A2 + (size_t)gm * Dv + ((sig & 3) << 3);
    }
    // B staging: 2 positions/thread (1024 x 16B = 16 KB)
    const unsigned short* pBs[2];
#pragma unroll
    for (int c = 0; c < 2; ++c) {
        const int p = tid + c * 512;
        const int L = p >> 3, s = p & 7;
        const int sig = s ^ (L & 7);
        pBs[c] = WT + (size_t)(2 * L + (sig >> 2)) * 512 + ((sig & 3) << 3);
    }

#define STAGE(bufv, k0v)                                                          \
    {                                                                             \
        if ((k0v) < 256) {                                                        \
            gload16(pA1s[0] + (k0v), &Asb[bufv][tid * 8]);                        \
            gload16(pA1s[1] + (k0v), &Asb[bufv][(tid + 512) * 8]);                \
        } else {                                                                  \
            gload16(pA2s[0] + ((k0v) - 256), &Asb[bufv][tid * 8]);                \
            gload16(pA2s[1] + ((k0v) - 256), &Asb[bufv][(tid + 512) * 8]);        \
        }                                                                         \
        gload16(pBs[0] + (k0v), &Bsb[bufv][tid * 8]);                             \
        gload16(pBs[1] + (k0v), &Bsb[bufv][(tid + 512) * 8]);                     \
    }

    // fragment read offsets (per-lane constants)
    const int q  = lane >> 4;
    const int fr = lane & 15;
    int aoff[8];
#pragma unroll
    for (int i = 0; i < 8; ++i) {
        const int r = wrow * 128 + i * 16 + fr;
        const int L = r >> 1;
        aoff[i] = L * 64 + (((((r & 1) << 2) + q) ^ (L & 7)) << 3);
    }
    int boff[4];
#pragma unroll
    for (int j = 0; j < 4; ++j) {
        const int n = wcol * 64 + j * 16 + fr;
        const int Lb = n >> 1;
        boff[j] = Lb * 64 + (((((n & 1) << 2) + q) ^ (Lb & 7)) << 3);
    }

    f32x4 acc[8][4] = {};

    STAGE(0, 0);
    asm volatile("" ::: "memory");    // pin vmcnt issue order between stages
    STAGE(1, 32);

#pragma unroll
    for (int t = 0; t < 16; ++t) {
        if (t < 15) asm volatile("s_waitcnt vmcnt(4)" ::: "memory");
        else        asm volatile("s_waitcnt vmcnt(0)" ::: "memory");
        __builtin_amdgcn_s_barrier();            // tile t fully in LDS

        const int cur = t & 1;
        s16x8 af[8], bfv[4];
#pragma unroll
        for (int j = 0; j < 4; ++j)
            bfv[j] = *(const s16x8*)&Bsb[cur][boff[j]];
#pragma unroll
        for (int i = 0; i < 8; ++i)
            af[i] = *(const s16x8*)&Asb[cur][aoff[i]];
#pragma unroll
        for (int i = 0; i < 8; ++i)
#pragma unroll
            for (int j = 0; j < 4; ++j)
                acc[i][j] = __builtin_amdgcn_mfma_f32_16x16x32_bf16(af[i], bfv[j], acc[i][j], 0, 0, 0);

        asm volatile("s_waitcnt lgkmcnt(0)" ::: "memory");  // my ds_reads landed
        __builtin_amdgcn_s_barrier();                       // all waves done with buf
        if (t < 14) STAGE(t & 1, (t + 2) * 32);             // overwrite is now safe
    }
#undef STAGE

    // epilogue: C/D map col=lane&15, row=(lane>>4)*4+reg
#pragma unroll
    for (int i = 0; i < 8; ++i) {
#pragma unroll
        for (int reg = 0; reg < 4; ++reg) {
            const int gr = m0 + wrow * 128 + i * 16 + q * 4 + reg;
            if (gr < M) {
#pragma unroll
                for (int j = 0; j < 4; ++j) {
                    const int gc = wcol * 64 + j * 16 + fr;
                    float v = acc[i][j][reg] + bias[gc];
                    if (RELU) v = fmaxf(v, 0.0f);
                    if (OUTBF)
                        ((unsigned short*)outp)[(size_t)gr * ldc + col_off + gc] = f2bf(v);
                    else
                        ((float*)outp)[(size_t)gr * ldc + col_off + gc] = v;
                }
            }
        }
    }
}

// ---- post: logits = ocat(bf16, 10000x512) @ W_post(512x40) + b_post; log_softmax.
__global__ __launch_bounds__(256) void post_kernel(
    const unsigned short* __restrict__ ocat, const float* __restrict__ Wp,
    const float* __restrict__ bp, float* __restrict__ out, int nrows)
{
    __shared__ float sW[512 * 40];        // 80 KB
    __shared__ float sP[7][32][40];       // 35 KB partials (q=1..7)
    __shared__ float sb[Cv];

    const int tid = threadIdx.x;

    for (int i = tid; i < 5120; i += 256)
        ((float4*)sW)[i] = ((const float4*)Wp)[i];
    if (tid < Cv) sb[tid] = bp[tid];
    __syncthreads();

    const int q = tid >> 5;               // k-split 0..7 (64 k each)
    const int r = tid & 31;               // local row
    const int t = blockIdx.x * 32 + r;
    const bool valid = (t < nrows);

    float acc[Cv] = {};
    if (valid) {
        const unsigned short* prow = ocat + (size_t)t * 512 + q * 64;
        for (int kk = 0; kk < 64; kk += 8) {
            u16x8 v = *(const u16x8*)(prow + kk);
            const float* wbase = &sW[(q * 64 + kk) * Cv];
#pragma unroll
            for (int e = 0; e < 8; ++e) {
                const float xv = bf2f(v[e]);
                const float* wr_ = wbase + e * Cv;
#pragma unroll
                for (int c4 = 0; c4 < Cv; c4 += 4) {
                    f32x4 wv = *(const f32x4*)(wr_ + c4);
                    acc[c4 + 0] += xv * wv[0];
                    acc[c4 + 1] += xv * wv[1];
                    acc[c4 + 2] += xv * wv[2];
                    acc[c4 + 3] += xv * wv[3];
                }
            }
        }
    }

    if (q > 0) {
#pragma unroll
        for (int c4 = 0; c4 < Cv; c4 += 4)
            *(f32x4*)&sP[q - 1][r][c4] = *(f32x4*)&acc[c4];
    }
    __syncthreads();

    if (q == 0 && valid) {
#pragma unroll
        for (int p = 0; p < 7; ++p)
#pragma unroll
            for (int c4 = 0; c4 < Cv; c4 += 4) {
                f32x4 pv = *(const f32x4*)&sP[p][r][c4];
                acc[c4 + 0] += pv[0];
                acc[c4 + 1] += pv[1];
                acc[c4 + 2] += pv[2];
                acc[c4 + 3] += pv[3];
            }
        float m = -INFINITY;
#pragma unroll
        for (int c = 0; c < Cv; ++c) { acc[c] += sb[c]; m = fmaxf(m, acc[c]); }
        float s = 0.0f;
#pragma unroll
        for (int c = 0; c < Cv; ++c) s += expf(acc[c] - m);
        const float lse = m + logf(s);
        float* dst = out + (size_t)t * Cv;
#pragma unroll
        for (int c4 = 0; c4 < Cv; c4 += 4) {
            float o[4] = { acc[c4] - lse, acc[c4 + 1] - lse, acc[c4 + 2] - lse, acc[c4 + 3] - lse };
            *(float4*)(dst + c4) = *(float4*)o;
        }
    }
}

extern "C" void kernel_launch(void* const* d_in, const int* in_sizes, int n_in,
                              void* d_out, int out_size, void* d_ws, size_t ws_size,
                              hipStream_t stream)
{
    const float* x      = (const float*)d_in[0];
    const int*   ei0    = (const int*)d_in[1];
    const int*   ei1    = (const int*)d_in[2];
    const float* Wl_m0  = (const float*)d_in[3];
    const float* Wr_m0  = (const float*)d_in[4];
    const float* b_m0   = (const float*)d_in[5];
    const float* Wl_x0  = (const float*)d_in[6];
    const float* Wr_x0  = (const float*)d_in[7];
    const float* b_x0   = (const float*)d_in[8];
    const float* Wl_m1  = (const float*)d_in[9];
    const float* Wr_m1  = (const float*)d_in[10];
    const float* b_m1   = (const float*)d_in[11];
    const float* Wl_x1  = (const float*)d_in[12];
    const float* Wr_x1  = (const float*)d_in[13];
    const float* b_x1   = (const float*)d_in[14];
    const float* W_post = (const float*)d_in[15];
    const float* b_post = (const float*)d_in[16];
    float* out = (float*)d_out;

    const int* row0 = ei0;   // edge_index0[0]
    const int* row1 = ei1;   // edge_index1[0]

    // workspace layout
    char* ws = (char*)d_ws;
    const size_t XB = (size_t)N0v * Dv * 2;                        // 102.4 MB
    const size_t NB = (size_t)N1v * Dv * 2;                        // 25.6 MB
    unsigned short* xb  = (unsigned short*)(ws);                   // x bf16 (full table)
    unsigned short* am  = (unsigned short*)(ws + XB);
    unsigned short* ax  = (unsigned short*)(ws + XB + NB);
    unsigned short* hm  = (unsigned short*)(ws + XB + 2 * NB);
    unsigned short* hx  = (unsigned short*)(ws + XB + 3 * NB);
    unsigned short* a1m = (unsigned short*)(ws + XB + 4 * NB);
    unsigned short* a1x = a1m + (size_t)N2v * Dv;
    unsigned short* ocat = (unsigned short*)(ws + XB + 4 * NB + (size_t)2 * N2v * Dv * 2);
    unsigned short* WT0m = ocat + (size_t)N2v * 2 * Dv;
    unsigned short* WT0x = WT0m + (size_t)256 * 512;
    unsigned short* WT1m = WT0x + (size_t)256 * 512;
    unsigned short* WT1x = WT1m + (size_t)256 * 512;

    const dim3 blk(256);

    // 1) x -> bf16 table + weight transposes (one streaming dispatch)
    conv_prep_kernel<<<25000 + 1024, blk, 0, stream>>>(
        x, xb,
        Wl_m0, Wr_m0, Wl_x0, Wr_x0, Wl_m1, Wr_m1, Wl_x1, Wr_x1,
        WT0m, WT0x, WT1m, WT1x);

    // 2) layer-0 aggregation from L3-resident bf16 table
    agg0_kernel<<<N1v / 8, blk, 0, stream>>>(xb, row0, am, ax);

    // 3) layer 0 GEMMs (one dispatch, 256x256 pipelined); A2 = xb[:50000]
    gemm_pipe_kernel<1, 1><<<dim3((N1v + 255) / 256, 1, 2), dim3(512), 0, stream>>>(
        am, ax, xb, WT0m, WT0x, b_m0, b_x0, hm, hx, N1v, Dv, 0);

    // 4) layer 1
    agg1_kernel<<<N2v / 8, blk, 0, stream>>>(hm, hx, row1, a1m, a1x);
    gemm_pipe_kernel<0, 1><<<dim3((N2v + 255) / 256, 1, 2), dim3(512), 0, stream>>>(
        a1m, a1x, xb, WT1m, WT1x, b_m1, b_x1, ocat, ocat, N2v, 2 * Dv, Dv);

    // 5) post
    post_kernel<<<(N2v + 31) / 32, blk, 0, stream>>>(ocat, W_post, b_post, out, N2v);
}

// Round 12
// 218.354 us; speedup vs baseline: 1.0181x; 1.0181x over previous
//
#include <hip/hip_runtime.h>
#include <hip/hip_bf16.h>
#include <math.h>

#define N0v 200000
#define N1v 50000
#define N2v 10000
#define Dv  256
#define Cv  40
#define DEGv 10

typedef __attribute__((ext_vector_type(8))) short          s16x8;
typedef __attribute__((ext_vector_type(8))) unsigned short u16x8;
typedef __attribute__((ext_vector_type(4))) float          f32x4;

static __device__ __forceinline__ unsigned short f2bf(float f) {
    __hip_bfloat16 h = __float2bfloat16(f);
    return *reinterpret_cast<unsigned short*>(&h);
}
static __device__ __forceinline__ float bf2f(unsigned short u) {
    __hip_bfloat16 h = *reinterpret_cast<__hip_bfloat16*>(&u);
    return __bfloat162float(h);
}

// async global -> LDS, 16B/lane, wave-uniform LDS base + lane*16 dest
static __device__ __forceinline__ void gload16(const void* g, void* l) {
    __builtin_amdgcn_global_load_lds(
        (const __attribute__((address_space(1))) unsigned int*)g,
        (__attribute__((address_space(3))) unsigned int*)l, 16, 0, 0);
}

// ---- conv+prep: blocks [0,2048) grid-stride convert x (200000x256 f32) -> xb bf16;
//      blocks [2048,3072) transpose 4 weight pairs -> WT[n][k] bf16.
__global__ __launch_bounds__(256) void conv_prep_kernel(
    const float* __restrict__ x, unsigned short* __restrict__ xb,
    const float* __restrict__ Wl0, const float* __restrict__ Wr0,
    const float* __restrict__ Wl1, const float* __restrict__ Wr1,
    const float* __restrict__ Wl2, const float* __restrict__ Wr2,
    const float* __restrict__ Wl3, const float* __restrict__ Wr3,
    unsigned short* __restrict__ WT0, unsigned short* __restrict__ WT1,
    unsigned short* __restrict__ WT2, unsigned short* __restrict__ WT3)
{
    const int b = blockIdx.x;
    const int tid = threadIdx.x;
    if (b < 2048) {
        const size_t ngroups = (size_t)N0v * Dv / 8;            // 6.4M x 8 elems
        const size_t stride = (size_t)2048 * 256;
        for (size_t g = (size_t)b * 256 + tid; g < ngroups; g += stride) {
            const size_t i = g * 8;
            float4 v0 = *(const float4*)(x + i);
            float4 v1 = *(const float4*)(x + i + 4);
            unsigned short o[8] = { f2bf(v0.x), f2bf(v0.y), f2bf(v0.z), f2bf(v0.w),
                                    f2bf(v1.x), f2bf(v1.y), f2bf(v1.z), f2bf(v1.w) };
            *(u16x8*)(xb + i) = *(u16x8*)o;
        }
    } else {
        const int idx = b - 2048;
        const int p = idx >> 8;
        const int n = idx & 255;
        const float* Wl = (p == 0) ? Wl0 : (p == 1) ? Wl1 : (p == 2) ? Wl2 : Wl3;
        const float* Wr = (p == 0) ? Wr0 : (p == 1) ? Wr1 : (p == 2) ? Wr2 : Wr3;
        unsigned short* WT = (p == 0) ? WT0 : (p == 1) ? WT1 : (p == 2) ? WT2 : WT3;
        WT[(size_t)n * 512 + tid]       = f2bf(Wl[(size_t)tid * Dv + n]);
        WT[(size_t)n * 512 + 256 + tid] = f2bf(Wr[(size_t)tid * Dv + n]);
    }
}

// ---- layer-0 aggregation from bf16 table: one load feeds mean AND max.
__global__ __launch_bounds__(256) void agg0_kernel(
    const unsigned short* __restrict__ xb, const int* __restrict__ row,
    unsigned short* __restrict__ om, unsigned short* __restrict__ ox)
{
    const int t = blockIdx.x * 8 + (threadIdx.x >> 5);
    const int c = threadIdx.x & 31;
    const int eb = t * DEGv;
    float s[8] = {};
    float mx[8] = { -INFINITY, -INFINITY, -INFINITY, -INFINITY,
                    -INFINITY, -INFINITY, -INFINITY, -INFINITY };
#pragma unroll
    for (int k = 0; k < DEGv; ++k) {
        const int r = row[eb + k];
        u16x8 v = ((const u16x8*)xb)[(size_t)r * 32 + c];
#pragma unroll
        for (int j = 0; j < 8; ++j) {
            const float f = bf2f(v[j]);
            s[j] += f;
            mx[j] = fmaxf(mx[j], f);
        }
    }
    const float inv = 1.0f / DEGv;
    unsigned short osum[8], omax[8];
#pragma unroll
    for (int j = 0; j < 8; ++j) { osum[j] = f2bf(s[j] * inv); omax[j] = f2bf(mx[j]); }
    *(u16x8*)&om[(size_t)t * Dv + c * 8] = *(u16x8*)osum;
    *(u16x8*)&ox[(size_t)t * Dv + c * 8] = *(u16x8*)omax;
}

// ---- layer-1 aggregation: gather bf16 (u16x8/lane), write mean & max bf16
__global__ __launch_bounds__(256) void agg1_kernel(
    const unsigned short* __restrict__ hm, const unsigned short* __restrict__ hx,
    const int* __restrict__ row,
    unsigned short* __restrict__ om, unsigned short* __restrict__ ox)
{
    const int t = blockIdx.x * 8 + (threadIdx.x >> 5);
    const int c = threadIdx.x & 31;
    const int eb = t * DEGv;
    float s[8] = {};
    float mx[8] = { -INFINITY, -INFINITY, -INFINITY, -INFINITY,
                    -INFINITY, -INFINITY, -INFINITY, -INFINITY };
#pragma unroll
    for (int k = 0; k < DEGv; ++k) {
        const int r = row[eb + k];
        u16x8 vm = ((const u16x8*)hm)[(size_t)r * 32 + c];
        u16x8 vx = ((const u16x8*)hx)[(size_t)r * 32 + c];
#pragma unroll
        for (int j = 0; j < 8; ++j) {
            s[j]  += bf2f(vm[j]);
            mx[j]  = fmaxf(mx[j], bf2f(vx[j]));
        }
    }
    const float inv = 1.0f / DEGv;
    unsigned short osum[8], omax[8];
#pragma unroll
    for (int j = 0; j < 8; ++j) { osum[j] = f2bf(s[j] * inv); omax[j] = f2bf(mx[j]); }
    *(u16x8*)&om[(size_t)t * Dv + c * 8] = *(u16x8*)osum;
    *(u16x8*)&ox[(size_t)t * Dv + c * 8] = *(u16x8*)omax;
}

// ---- bf16 MFMA GEMM, counted-vmcnt 2-deep pipeline (r10-proven best):
// out_z = [relu]( [A1_z|A2] (Mx512) @ WT_z^T + bias_z )
// BM=128, BN=256, BK=32, 512 threads = 8 waves (2M x 4N), wave-tile 64x64.
// LDS paired-line layout: line L (64 elems) = rows {2L,2L+1} x 32 k; phys
// 8-elem slot s of line L holds logical sig = s ^ (L&7), sig = (row&1)*4 + q.
// Staging: 3 x gload16/thread/stage, linear dest, pre-swizzled source.
// Schedule/iter: vmcnt(3); barrier; ds_read+16 MFMA; lgkmcnt(0); barrier;
// STAGE(t+2).  vmcnt never drains to 0 in the main loop.
template<int RELU, int OUTBF>
__global__ __launch_bounds__(512) void gemm_pipe_kernel(
    const unsigned short* __restrict__ A1a, const unsigned short* __restrict__ A1b,
    const unsigned short* __restrict__ A2,
    const unsigned short* __restrict__ WTa, const unsigned short* __restrict__ WTb,
    const float* __restrict__ biasa, const float* __restrict__ biasb,
    void* outa, void* outb, int M, int ldc, int col_step)
{
    __shared__ unsigned short Asb[2][4096];   // 2 x 8 KB  (128 rows x 32 k)
    __shared__ unsigned short Bsb[2][8192];   // 2 x 16 KB (256 rows x 32 k)

    const int z = blockIdx.z;
    const unsigned short* A1 = z ? A1b : A1a;
    const unsigned short* WT = z ? WTb : WTa;
    const float* bias = z ? biasb : biasa;
    void* outp = z ? outb : outa;
    const int col_off = z * col_step;

    const int tid  = threadIdx.x;
    const int lane = tid & 63;
    const int w    = tid >> 6;
    const int wrow = w >> 2;          // 0..1 (x64 rows)
    const int wcol = w & 3;           // 0..3 (x64 cols)
    const int m0   = blockIdx.x * 128;

    // A staging descriptor: 1 position/thread (512 x 16B = 8 KB)
    const unsigned short *pA1s, *pA2s;
    {
        const int L = tid >> 3, s = tid & 7;
        const int sig = s ^ (L & 7);
        int gm = m0 + 2 * L + (sig >> 2);
        if (gm >= M) gm = M - 1;
        pA1s = A1 + (size_t)gm * Dv + ((sig & 3) << 3);
        pA2s = A2 + (size_t)gm * Dv + ((sig & 3) << 3);
    }
    // B staging: 2 positions/thread (1024 x 16B = 16 KB)
    const unsigned short* pBs[2];
#pragma unroll
    for (int c = 0; c < 2; ++c) {
        const int p = tid + c * 512;
        const int L = p >> 3, s = p & 7;
        const int sig = s ^ (L & 7);
        pBs[c] = WT + (size_t)(2 * L + (sig >> 2)) * 512 + ((sig & 3) << 3);
    }

#define STAGE(bufv, k0v)                                                      \
    {                                                                         \
        if ((k0v) < 256) gload16(pA1s + (k0v), &Asb[bufv][tid * 8]);          \
        else             gload16(pA2s + ((k0v) - 256), &Asb[bufv][tid * 8]);  \
        gload16(pBs[0] + (k0v), &Bsb[bufv][tid * 8]);                         \
        gload16(pBs[1] + (k0v), &Bsb[bufv][(tid + 512) * 8]);                 \
    }

    // fragment read offsets (per-lane constants)
    const int q  = lane >> 4;
    const int fr = lane & 15;
    int aoff[4], boff[4];
#pragma unroll
    for (int i = 0; i < 4; ++i) {
        const int r = wrow * 64 + i * 16 + fr;
        const int L = r >> 1;
        aoff[i] = L * 64 + (((((r & 1) << 2) + q) ^ (L & 7)) << 3);
        const int n = wcol * 64 + i * 16 + fr;
        const int Lb = n >> 1;
        boff[i] = Lb * 64 + (((((n & 1) << 2) + q) ^ (Lb & 7)) << 3);
    }

    f32x4 acc[4][4] = {};

    STAGE(0, 0);
    asm volatile("" ::: "memory");    // pin vmcnt issue order between stages
    STAGE(1, 32);

#pragma unroll
    for (int t = 0; t < 16; ++t) {
        if (t < 15) asm volatile("s_waitcnt vmcnt(3)" ::: "memory");
        else        asm volatile("s_waitcnt vmcnt(0)" ::: "memory");
        __builtin_amdgcn_s_barrier();            // tile t fully in LDS

        const int cur = t & 1;
        s16x8 af[4], bfv[4];
#pragma unroll
        for (int i = 0; i < 4; ++i) {
            af[i]  = *(const s16x8*)&Asb[cur][aoff[i]];
            bfv[i] = *(const s16x8*)&Bsb[cur][boff[i]];
        }
#pragma unroll
        for (int j = 0; j < 4; ++j)
#pragma unroll
            for (int i = 0; i < 4; ++i)
                acc[i][j] = __builtin_amdgcn_mfma_f32_16x16x32_bf16(af[i], bfv[j], acc[i][j], 0, 0, 0);

        asm volatile("s_waitcnt lgkmcnt(0)" ::: "memory");  // my ds_reads landed
        __builtin_amdgcn_s_barrier();                       // all waves done with buf
        if (t < 14) STAGE(t & 1, (t + 2) * 32);             // overwrite is now safe
    }
#undef STAGE

    // epilogue: C/D map col=lane&15, row=(lane>>4)*4+reg
#pragma unroll
    for (int i = 0; i < 4; ++i) {
#pragma unroll
        for (int reg = 0; reg < 4; ++reg) {
            const int gr = m0 + wrow * 64 + i * 16 + q * 4 + reg;
            if (gr < M) {
#pragma unroll
                for (int j = 0; j < 4; ++j) {
                    const int gc = wcol * 64 + j * 16 + fr;
                    float v = acc[i][j][reg] + bias[gc];
                    if (RELU) v = fmaxf(v, 0.0f);
                    if (OUTBF)
                        ((unsigned short*)outp)[(size_t)gr * ldc + col_off + gc] = f2bf(v);
                    else
                        ((float*)outp)[(size_t)gr * ldc + col_off + gc] = v;
                }
            }
        }
    }
}

// ---- post: logits = ocat(bf16, 10000x512) @ W_post(512x40) + b_post; log_softmax.
__global__ __launch_bounds__(256) void post_kernel(
    const unsigned short* __restrict__ ocat, const float* __restrict__ Wp,
    const float* __restrict__ bp, float* __restrict__ out, int nrows)
{
    __shared__ float sW[512 * 40];        // 80 KB
    __shared__ float sP[7][32][40];       // 35 KB partials (q=1..7)
    __shared__ float sb[Cv];

    const int tid = threadIdx.x;

    for (int i = tid; i < 5120; i += 256)
        ((float4*)sW)[i] = ((const float4*)Wp)[i];
    if (tid < Cv) sb[tid] = bp[tid];
    __syncthreads();

    const int q = tid >> 5;               // k-split 0..7 (64 k each)
    const int r = tid & 31;               // local row
    const int t = blockIdx.x * 32 + r;
    const bool valid = (t < nrows);

    float acc[Cv] = {};
    if (valid) {
        const unsigned short* prow = ocat + (size_t)t * 512 + q * 64;
        for (int kk = 0; kk < 64; kk += 8) {
            u16x8 v = *(const u16x8*)(prow + kk);
            const float* wbase = &sW[(q * 64 + kk) * Cv];
#pragma unroll
            for (int e = 0; e < 8; ++e) {
                const float xv = bf2f(v[e]);
                const float* wr_ = wbase + e * Cv;
#pragma unroll
                for (int c4 = 0; c4 < Cv; c4 += 4) {
                    f32x4 wv = *(const f32x4*)(wr_ + c4);
                    acc[c4 + 0] += xv * wv[0];
                    acc[c4 + 1] += xv * wv[1];
                    acc[c4 + 2] += xv * wv[2];
                    acc[c4 + 3] += xv * wv[3];
                }
            }
        }
    }

    if (q > 0) {
#pragma unroll
        for (int c4 = 0; c4 < Cv; c4 += 4)
            *(f32x4*)&sP[q - 1][r][c4] = *(f32x4*)&acc[c4];
    }
    __syncthreads();

    if (q == 0 && valid) {
#pragma unroll
        for (int p = 0; p < 7; ++p)
#pragma unroll
            for (int c4 = 0; c4 < Cv; c4 += 4) {
                f32x4 pv = *(const f32x4*)&sP[p][r][c4];
                acc[c4 + 0] += pv[0];
                acc[c4 + 1] += pv[1];
                acc[c4 + 2] += pv[2];
                acc[c4 + 3] += pv[3];
            }
        float m = -INFINITY;
#pragma unroll
        for (int c = 0; c < Cv; ++c) { acc[c] += sb[c]; m = fmaxf(m, acc[c]); }
        float s = 0.0f;
#pragma unroll
        for (int c = 0; c < Cv; ++c) s += expf(acc[c] - m);
        const float lse = m + logf(s);
        float* dst = out + (size_t)t * Cv;
#pragma unroll
        for (int c4 = 0; c4 < Cv; c4 += 4) {
            float o[4] = { acc[c4] - lse, acc[c4 + 1] - lse, acc[c4 + 2] - lse, acc[c4 + 3] - lse };
            *(float4*)(dst + c4) = *(float4*)o;
        }
    }
}

extern "C" void kernel_launch(void* const* d_in, const int* in_sizes, int n_in,
                              void* d_out, int out_size, void* d_ws, size_t ws_size,
                              hipStream_t stream)
{
    const float* x      = (const float*)d_in[0];
    const int*   ei0    = (const int*)d_in[1];
    const int*   ei1    = (const int*)d_in[2];
    const float* Wl_m0  = (const float*)d_in[3];
    const float* Wr_m0  = (const float*)d_in[4];
    const float* b_m0   = (const float*)d_in[5];
    const float* Wl_x0  = (const float*)d_in[6];
    const float* Wr_x0  = (const float*)d_in[7];
    const float* b_x0   = (const float*)d_in[8];
    const float* Wl_m1  = (const float*)d_in[9];
    const float* Wr_m1  = (const float*)d_in[10];
    const float* b_m1   = (const float*)d_in[11];
    const float* Wl_x1  = (const float*)d_in[12];
    const float* Wr_x1  = (const float*)d_in[13];
    const float* b_x1   = (const float*)d_in[14];
    const float* W_post = (const float*)d_in[15];
    const float* b_post = (const float*)d_in[16];
    float* out = (float*)d_out;

    const int* row0 = ei0;   // edge_index0[0]
    const int* row1 = ei1;   // edge_index1[0]

    // workspace layout
    char* ws = (char*)d_ws;
    const size_t XB = (size_t)N0v * Dv * 2;                        // 102.4 MB
    const size_t NB = (size_t)N1v * Dv * 2;                        // 25.6 MB
    unsigned short* xb  = (unsigned short*)(ws);                   // x bf16 (full table)
    unsigned short* am  = (unsigned short*)(ws + XB);
    unsigned short* ax  = (unsigned short*)(ws + XB + NB);
    unsigned short* hm  = (unsigned short*)(ws + XB + 2 * NB);
    unsigned short* hx  = (unsigned short*)(ws + XB + 3 * NB);
    unsigned short* a1m = (unsigned short*)(ws + XB + 4 * NB);
    unsigned short* a1x = a1m + (size_t)N2v * Dv;
    unsigned short* ocat = (unsigned short*)(ws + XB + 4 * NB + (size_t)2 * N2v * Dv * 2);
    unsigned short* WT0m = ocat + (size_t)N2v * 2 * Dv;
    unsigned short* WT0x = WT0m + (size_t)256 * 512;
    unsigned short* WT1m = WT0x + (size_t)256 * 512;
    unsigned short* WT1x = WT1m + (size_t)256 * 512;

    const dim3 blk(256);

    // 1) x -> bf16 table (grid-stride) + weight transposes (one dispatch)
    conv_prep_kernel<<<2048 + 1024, blk, 0, stream>>>(
        x, xb,
        Wl_m0, Wr_m0, Wl_x0, Wr_x0, Wl_m1, Wr_m1, Wl_x1, Wr_x1,
        WT0m, WT0x, WT1m, WT1x);

    // 2) layer-0 aggregation from L3-resident bf16 table
    agg0_kernel<<<N1v / 8, blk, 0, stream>>>(xb, row0, am, ax);

    // 3) layer 0 GEMMs (one dispatch, pipelined); A2 = xb[:50000]
    gemm_pipe_kernel<1, 1><<<dim3((N1v + 127) / 128, 1, 2), dim3(512), 0, stream>>>(
        am, ax, xb, WT0m, WT0x, b_m0, b_x0, hm, hx, N1v, Dv, 0);

    // 4) layer 1
    agg1_kernel<<<N2v / 8, blk, 0, stream>>>(hm, hx, row1, a1m, a1x);
    gemm_pipe_kernel<0, 1><<<dim3((N2v + 127) / 128, 1, 2), dim3(512), 0, stream>>>(
        a1m, a1x, xb, WT1m, WT1x, b_m1, b_x1, ocat, ocat, N2v, 2 * Dv, Dv);

    // 5) post
    post_kernel<<<(N2v + 31) / 32, blk, 0, stream>>>(ocat, W_post, b_post, out, N2v);
}

// Round 13
// 215.682 us; speedup vs baseline: 1.0307x; 1.0124x over previous
//
#include <hip/hip_runtime.h>
#include <hip/hip_bf16.h>
#include <math.h>

#define N0v 200000
#define N1v 50000
#define N2v 10000
#define Dv  256
#define Cv  40
#define DEGv 10

typedef __attribute__((ext_vector_type(8))) short          s16x8;
typedef __attribute__((ext_vector_type(8))) unsigned short u16x8;
typedef __attribute__((ext_vector_type(4))) float          f32x4;

static __device__ __forceinline__ unsigned short f2bf(float f) {
    __hip_bfloat16 h = __float2bfloat16(f);
    return *reinterpret_cast<unsigned short*>(&h);
}
static __device__ __forceinline__ float bf2f(unsigned short u) {
    __hip_bfloat16 h = *reinterpret_cast<__hip_bfloat16*>(&u);
    return __bfloat162float(h);
}

// async global -> LDS, 16B/lane, wave-uniform LDS base + lane*16 dest
static __device__ __forceinline__ void gload16(const void* g, void* l) {
    __builtin_amdgcn_global_load_lds(
        (const __attribute__((address_space(1))) unsigned int*)g,
        (__attribute__((address_space(3))) unsigned int*)l, 16, 0, 0);
}

// ---- conv+prep: blocks [0,25000) convert x (200000x256 f32) -> xb bf16;
//      blocks [25000,26024) transpose 4 weight pairs -> WT[n][k] bf16.
__global__ __launch_bounds__(256) void conv_prep_kernel(
    const float* __restrict__ x, unsigned short* __restrict__ xb,
    const float* __restrict__ Wl0, const float* __restrict__ Wr0,
    const float* __restrict__ Wl1, const float* __restrict__ Wr1,
    const float* __restrict__ Wl2, const float* __restrict__ Wr2,
    const float* __restrict__ Wl3, const float* __restrict__ Wr3,
    unsigned short* __restrict__ WT0, unsigned short* __restrict__ WT1,
    unsigned short* __restrict__ WT2, unsigned short* __restrict__ WT3)
{
    const int b = blockIdx.x;
    const int tid = threadIdx.x;
    if (b < 25000) {
        const size_t i = ((size_t)b * 256 + tid) * 8;
        float4 v0 = *(const float4*)(x + i);
        float4 v1 = *(const float4*)(x + i + 4);
        unsigned short o[8] = { f2bf(v0.x), f2bf(v0.y), f2bf(v0.z), f2bf(v0.w),
                                f2bf(v1.x), f2bf(v1.y), f2bf(v1.z), f2bf(v1.w) };
        *(u16x8*)(xb + i) = *(u16x8*)o;
    } else {
        const int idx = b - 25000;
        const int p = idx >> 8;
        const int n = idx & 255;
        const float* Wl = (p == 0) ? Wl0 : (p == 1) ? Wl1 : (p == 2) ? Wl2 : Wl3;
        const float* Wr = (p == 0) ? Wr0 : (p == 1) ? Wr1 : (p == 2) ? Wr2 : Wr3;
        unsigned short* WT = (p == 0) ? WT0 : (p == 1) ? WT1 : (p == 2) ? WT2 : WT3;
        WT[(size_t)n * 512 + tid]       = f2bf(Wl[(size_t)tid * Dv + n]);
        WT[(size_t)n * 512 + 256 + tid] = f2bf(Wr[(size_t)tid * Dv + n]);
    }
}

// ---- layer-0 aggregation from bf16 table: one load feeds mean AND max.
__global__ __launch_bounds__(256) void agg0_kernel(
    const unsigned short* __restrict__ xb, const int* __restrict__ row,
    unsigned short* __restrict__ om, unsigned short* __restrict__ ox)
{
    const int t = blockIdx.x * 8 + (threadIdx.x >> 5);
    const int c = threadIdx.x & 31;
    const int eb = t * DEGv;
    float s[8] = {};
    float mx[8] = { -INFINITY, -INFINITY, -INFINITY, -INFINITY,
                    -INFINITY, -INFINITY, -INFINITY, -INFINITY };
#pragma unroll
    for (int k = 0; k < DEGv; ++k) {
        const int r = row[eb + k];
        u16x8 v = ((const u16x8*)xb)[(size_t)r * 32 + c];
#pragma unroll
        for (int j = 0; j < 8; ++j) {
            const float f = bf2f(v[j]);
            s[j] += f;
            mx[j] = fmaxf(mx[j], f);
        }
    }
    const float inv = 1.0f / DEGv;
    unsigned short osum[8], omax[8];
#pragma unroll
    for (int j = 0; j < 8; ++j) { osum[j] = f2bf(s[j] * inv); omax[j] = f2bf(mx[j]); }
    *(u16x8*)&om[(size_t)t * Dv + c * 8] = *(u16x8*)osum;
    *(u16x8*)&ox[(size_t)t * Dv + c * 8] = *(u16x8*)omax;
}

// ---- layer-1 aggregation: gather bf16 (u16x8/lane), write mean & max bf16
__global__ __launch_bounds__(256) void agg1_kernel(
    const unsigned short* __restrict__ hm, const unsigned short* __restrict__ hx,
    const int* __restrict__ row,
    unsigned short* __restrict__ om, unsigned short* __restrict__ ox)
{
    const int t = blockIdx.x * 8 + (threadIdx.x >> 5);
    const int c = threadIdx.x & 31;
    const int eb = t * DEGv;
    float s[8] = {};
    float mx[8] = { -INFINITY, -INFINITY, -INFINITY, -INFINITY,
                    -INFINITY, -INFINITY, -INFINITY, -INFINITY };
#pragma unroll
    for (int k = 0; k < DEGv; ++k) {
        const int r = row[eb + k];
        u16x8 vm = ((const u16x8*)hm)[(size_t)r * 32 + c];
        u16x8 vx = ((const u16x8*)hx)[(size_t)r * 32 + c];
#pragma unroll
        for (int j = 0; j < 8; ++j) {
            s[j]  += bf2f(vm[j]);
            mx[j]  = fmaxf(mx[j], bf2f(vx[j]));
        }
    }
    const float inv = 1.0f / DEGv;
    unsigned short osum[8], omax[8];
#pragma unroll
    for (int j = 0; j < 8; ++j) { osum[j] = f2bf(s[j] * inv); omax[j] = f2bf(mx[j]); }
    *(u16x8*)&om[(size_t)t * Dv + c * 8] = *(u16x8*)osum;
    *(u16x8*)&ox[(size_t)t * Dv + c * 8] = *(u16x8*)omax;
}

// ---- bf16 MFMA GEMM, counted-vmcnt 2-deep pipeline (r10-proven best):
// out_z = [relu]( [A1_z|A2] (Mx512) @ WT_z^T + bias_z )
// BM=128, BN=256, BK=32, 512 threads = 8 waves (2M x 4N), wave-tile 64x64.
// LDS paired-line layout: line L (64 elems) = rows {2L,2L+1} x 32 k; phys
// 8-elem slot s of line L holds logical sig = s ^ (L&7), sig = (row&1)*4 + q.
// Staging: 3 x gload16/thread/stage, linear dest, pre-swizzled source.
// Schedule/iter: vmcnt(3); barrier; ds_read+16 MFMA; lgkmcnt(0); barrier;
// STAGE(t+2).  vmcnt never drains to 0 in the main loop.
template<int RELU, int OUTBF>
__global__ __launch_bounds__(512) void gemm_pipe_kernel(
    const unsigned short* __restrict__ A1a, const unsigned short* __restrict__ A1b,
    const unsigned short* __restrict__ A2,
    const unsigned short* __restrict__ WTa, const unsigned short* __restrict__ WTb,
    const float* __restrict__ biasa, const float* __restrict__ biasb,
    void* outa, void* outb, int M, int ldc, int col_step)
{
    __shared__ unsigned short Asb[2][4096];   // 2 x 8 KB  (128 rows x 32 k)
    __shared__ unsigned short Bsb[2][8192];   // 2 x 16 KB (256 rows x 32 k)

    const int z = blockIdx.z;
    const unsigned short* A1 = z ? A1b : A1a;
    const unsigned short* WT = z ? WTb : WTa;
    const float* bias = z ? biasb : biasa;
    void* outp = z ? outb : outa;
    const int col_off = z * col_step;

    const int tid  = threadIdx.x;
    const int lane = tid & 63;
    const int w    = tid >> 6;
    const int wrow = w >> 2;          // 0..1 (x64 rows)
    const int wcol = w & 3;           // 0..3 (x64 cols)
    const int m0   = blockIdx.x * 128;

    // A staging descriptor: 1 position/thread (512 x 16B = 8 KB)
    const unsigned short *pA1s, *pA2s;
    {
        const int L = tid >> 3, s = tid & 7;
        const int sig = s ^ (L & 7);
        int gm = m0 + 2 * L + (sig >> 2);
        if (gm >= M) gm = M - 1;
        pA1s = A1 + (size_t)gm * Dv + ((sig & 3) << 3);
        pA2s = A2 + (size_t)gm * Dv + ((sig & 3) << 3);
    }
    // B staging: 2 positions/thread (1024 x 16B = 16 KB)
    const unsigned short* pBs[2];
#pragma unroll
    for (int c = 0; c < 2; ++c) {
        const int p = tid + c * 512;
        const int L = p >> 3, s = p & 7;
        const int sig = s ^ (L & 7);
        pBs[c] = WT + (size_t)(2 * L + (sig >> 2)) * 512 + ((sig & 3) << 3);
    }

#define STAGE(bufv, k0v)                                                      \
    {                                                                         \
        if ((k0v) < 256) gload16(pA1s + (k0v), &Asb[bufv][tid * 8]);          \
        else             gload16(pA2s + ((k0v) - 256), &Asb[bufv][tid * 8]);  \
        gload16(pBs[0] + (k0v), &Bsb[bufv][tid * 8]);                         \
        gload16(pBs[1] + (k0v), &Bsb[bufv][(tid + 512) * 8]);                 \
    }

    // fragment read offsets (per-lane constants)
    const int q  = lane >> 4;
    const int fr = lane & 15;
    int aoff[4], boff[4];
#pragma unroll
    for (int i = 0; i < 4; ++i) {
        const int r = wrow * 64 + i * 16 + fr;
        const int L = r >> 1;
        aoff[i] = L * 64 + (((((r & 1) << 2) + q) ^ (L & 7)) << 3);
        const int n = wcol * 64 + i * 16 + fr;
        const int Lb = n >> 1;
        boff[i] = Lb * 64 + (((((n & 1) << 2) + q) ^ (Lb & 7)) << 3);
    }

    f32x4 acc[4][4] = {};

    STAGE(0, 0);
    asm volatile("" ::: "memory");    // pin vmcnt issue order between stages
    STAGE(1, 32);

#pragma unroll
    for (int t = 0; t < 16; ++t) {
        if (t < 15) asm volatile("s_waitcnt vmcnt(3)" ::: "memory");
        else        asm volatile("s_waitcnt vmcnt(0)" ::: "memory");
        __builtin_amdgcn_s_barrier();            // tile t fully in LDS

        const int cur = t & 1;
        s16x8 af[4], bfv[4];
#pragma unroll
        for (int i = 0; i < 4; ++i) {
            af[i]  = *(const s16x8*)&Asb[cur][aoff[i]];
            bfv[i] = *(const s16x8*)&Bsb[cur][boff[i]];
        }
#pragma unroll
        for (int j = 0; j < 4; ++j)
#pragma unroll
            for (int i = 0; i < 4; ++i)
                acc[i][j] = __builtin_amdgcn_mfma_f32_16x16x32_bf16(af[i], bfv[j], acc[i][j], 0, 0, 0);

        asm volatile("s_waitcnt lgkmcnt(0)" ::: "memory");  // my ds_reads landed
        __builtin_amdgcn_s_barrier();                       // all waves done with buf
        if (t < 14) STAGE(t & 1, (t + 2) * 32);             // overwrite is now safe
    }
#undef STAGE

    // epilogue: C/D map col=lane&15, row=(lane>>4)*4+reg
#pragma unroll
    for (int i = 0; i < 4; ++i) {
#pragma unroll
        for (int reg = 0; reg < 4; ++reg) {
            const int gr = m0 + wrow * 64 + i * 16 + q * 4 + reg;
            if (gr < M) {
#pragma unroll
                for (int j = 0; j < 4; ++j) {
                    const int gc = wcol * 64 + j * 16 + fr;
                    float v = acc[i][j][reg] + bias[gc];
                    if (RELU) v = fmaxf(v, 0.0f);
                    if (OUTBF)
                        ((unsigned short*)outp)[(size_t)gr * ldc + col_off + gc] = f2bf(v);
                    else
                        ((float*)outp)[(size_t)gr * ldc + col_off + gc] = v;
                }
            }
        }
    }
}

// ---- post: logits = ocat(bf16, 10000x512) @ W_post(512x40) + b_post; log_softmax.
__global__ __launch_bounds__(256) void post_kernel(
    const unsigned short* __restrict__ ocat, const float* __restrict__ Wp,
    const float* __restrict__ bp, float* __restrict__ out, int nrows)
{
    __shared__ float sW[512 * 40];        // 80 KB
    __shared__ float sP[7][32][40];       // 35 KB partials (q=1..7)
    __shared__ float sb[Cv];

    const int tid = threadIdx.x;

    for (int i = tid; i < 5120; i += 256)
        ((float4*)sW)[i] = ((const float4*)Wp)[i];
    if (tid < Cv) sb[tid] = bp[tid];
    __syncthreads();

    const int q = tid >> 5;               // k-split 0..7 (64 k each)
    const int r = tid & 31;               // local row
    const int t = blockIdx.x * 32 + r;
    const bool valid = (t < nrows);

    float acc[Cv] = {};
    if (valid) {
        const unsigned short* prow = ocat + (size_t)t * 512 + q * 64;
        for (int kk = 0; kk < 64; kk += 8) {
            u16x8 v = *(const u16x8*)(prow + kk);
            const float* wbase = &sW[(q * 64 + kk) * Cv];
#pragma unroll
            for (int e = 0; e < 8; ++e) {
                const float xv = bf2f(v[e]);
                const float* wr_ = wbase + e * Cv;
#pragma unroll
                for (int c4 = 0; c4 < Cv; c4 += 4) {
                    f32x4 wv = *(const f32x4*)(wr_ + c4);
                    acc[c4 + 0] += xv * wv[0];
                    acc[c4 + 1] += xv * wv[1];
                    acc[c4 + 2] += xv * wv[2];
                    acc[c4 + 3] += xv * wv[3];
                }
            }
        }
    }

    if (q > 0) {
#pragma unroll
        for (int c4 = 0; c4 < Cv; c4 += 4)
            *(f32x4*)&sP[q - 1][r][c4] = *(f32x4*)&acc[c4];
    }
    __syncthreads();

    if (q == 0 && valid) {
#pragma unroll
        for (int p = 0; p < 7; ++p)
#pragma unroll
            for (int c4 = 0; c4 < Cv; c4 += 4) {
                f32x4 pv = *(const f32x4*)&sP[p][r][c4];
                acc[c4 + 0] += pv[0];
                acc[c4 + 1] += pv[1];
                acc[c4 + 2] += pv[2];
                acc[c4 + 3] += pv[3];
            }
        float m = -INFINITY;
#pragma unroll
        for (int c = 0; c < Cv; ++c) { acc[c] += sb[c]; m = fmaxf(m, acc[c]); }
        float s = 0.0f;
#pragma unroll
        for (int c = 0; c < Cv; ++c) s += expf(acc[c] - m);
        const float lse = m + logf(s);
        float* dst = out + (size_t)t * Cv;
#pragma unroll
        for (int c4 = 0; c4 < Cv; c4 += 4) {
            float o[4] = { acc[c4] - lse, acc[c4 + 1] - lse, acc[c4 + 2] - lse, acc[c4 + 3] - lse };
            *(float4*)(dst + c4) = *(float4*)o;
        }
    }
}

extern "C" void kernel_launch(void* const* d_in, const int* in_sizes, int n_in,
                              void* d_out, int out_size, void* d_ws, size_t ws_size,
                              hipStream_t stream)
{
    const float* x      = (const float*)d_in[0];
    const int*   ei0    = (const int*)d_in[1];
    const int*   ei1    = (const int*)d_in[2];
    const float* Wl_m0  = (const float*)d_in[3];
    const float* Wr_m0  = (const float*)d_in[4];
    const float* b_m0   = (const float*)d_in[5];
    const float* Wl_x0  = (const float*)d_in[6];
    const float* Wr_x0  = (const float*)d_in[7];
    const float* b_x0   = (const float*)d_in[8];
    const float* Wl_m1  = (const float*)d_in[9];
    const float* Wr_m1  = (const float*)d_in[10];
    const float* b_m1   = (const float*)d_in[11];
    const float* Wl_x1  = (const float*)d_in[12];
    const float* Wr_x1  = (const float*)d_in[13];
    const float* b_x1   = (const float*)d_in[14];
    const float* W_post = (const float*)d_in[15];
    const float* b_post = (const float*)d_in[16];
    float* out = (float*)d_out;

    const int* row0 = ei0;   // edge_index0[0]
    const int* row1 = ei1;   // edge_index1[0]

    // workspace layout
    char* ws = (char*)d_ws;
    const size_t XB = (size_t)N0v * Dv * 2;                        // 102.4 MB
    const size_t NB = (size_t)N1v * Dv * 2;                        // 25.6 MB
    unsigned short* xb  = (unsigned short*)(ws);                   // x bf16 (full table)
    unsigned short* am  = (unsigned short*)(ws + XB);
    unsigned short* ax  = (unsigned short*)(ws + XB + NB);
    unsigned short* hm  = (unsigned short*)(ws + XB + 2 * NB);
    unsigned short* hx  = (unsigned short*)(ws + XB + 3 * NB);
    unsigned short* a1m = (unsigned short*)(ws + XB + 4 * NB);
    unsigned short* a1x = a1m + (size_t)N2v * Dv;
    unsigned short* ocat = (unsigned short*)(ws + XB + 4 * NB + (size_t)2 * N2v * Dv * 2);
    unsigned short* WT0m = ocat + (size_t)N2v * 2 * Dv;
    unsigned short* WT0x = WT0m + (size_t)256 * 512;
    unsigned short* WT1m = WT0x + (size_t)256 * 512;
    unsigned short* WT1x = WT1m + (size_t)256 * 512;

    const dim3 blk(256);

    // 1) x -> bf16 table + weight transposes (one streaming dispatch)
    conv_prep_kernel<<<25000 + 1024, blk, 0, stream>>>(
        x, xb,
        Wl_m0, Wr_m0, Wl_x0, Wr_x0, Wl_m1, Wr_m1, Wl_x1, Wr_x1,
        WT0m, WT0x, WT1m, WT1x);

    // 2) layer-0 aggregation from L3-resident bf16 table
    agg0_kernel<<<N1v / 8, blk, 0, stream>>>(xb, row0, am, ax);

    // 3) layer 0 GEMMs (one dispatch, pipelined); A2 = xb[:50000]
    gemm_pipe_kernel<1, 1><<<dim3((N1v + 127) / 128, 1, 2), dim3(512), 0, stream>>>(
        am, ax, xb, WT0m, WT0x, b_m0, b_x0, hm, hx, N1v, Dv, 0);

    // 4) layer 1
    agg1_kernel<<<N2v / 8, blk, 0, stream>>>(hm, hx, row1, a1m, a1x);
    gemm_pipe_kernel<0, 1><<<dim3((N2v + 127) / 128, 1, 2), dim3(512), 0, stream>>>(
        a1m, a1x, xb, WT1m, WT1x, b_m1, b_x1, ocat, ocat, N2v, 2 * Dv, Dv);

    // 5) post
    post_kernel<<<(N2v + 31) / 32, blk, 0, stream>>>(ocat, W_post, b_post, out, N2v);
}